// Round 11
// baseline (489.588 us; speedup 1.0000x reference)
//
#include <hip/hip_runtime.h>
#include <hip/hip_bf16.h>

typedef __bf16 bf16;
typedef __attribute__((ext_vector_type(8))) __bf16 bf16x8;
typedef __attribute__((ext_vector_type(4))) __bf16 bf16x4;
typedef __attribute__((ext_vector_type(4))) float f32x4;

static constexpr int NSEQ = 4;
static constexpr int LQ   = 512;
static constexpr int HQN  = 32;
static constexpr int HKVN = 8;
static constexpr int GQ   = 4;
static constexpr int DH   = 128;
static constexpr int BPS  = 64;     // blocks per sequence (2048/32)
static constexpr int SKV  = 2048;   // max kv length
static constexpr int KVB  = 64;     // kv tile (2 paged blocks)
static constexpr int QBL  = 32;     // l-rows per workgroup
static constexpr int VST  = 72;     // V LDS row stride (elems)

__device__ __forceinline__ bf16x8 cvt8(const float4& a, const float4& b) {
  bf16x8 o;
  o[0] = (bf16)a.x; o[1] = (bf16)a.y; o[2] = (bf16)a.z; o[3] = (bf16)a.w;
  o[4] = (bf16)b.x; o[5] = (bf16)b.y; o[6] = (bf16)b.z; o[7] = (bf16)b.w;
  return o;
}

// prepass 1: gather paged K + convert to bf16: kb[b][h][s][d]
__global__ void prep_k(const float* __restrict__ kc, const int* __restrict__ bt,
                       bf16* __restrict__ kb) {
  int e = (blockIdx.x * 256 + threadIdx.x) * 8;
  int d = e & 127;
  int s = (e >> 7) & 2047;
  int h = (e >> 18) & 7;
  int b = e >> 21;
  int pb = bt[b * BPS + (s >> 5)];
  const float* src = kc + (((size_t)pb * 32 + (s & 31)) * 8 + h) * 128 + d;
  float4 a = *(const float4*)src;
  float4 c = *(const float4*)(src + 4);
  *(bf16x8*)(kb + e) = cvt8(a, c);
}

// prepass 2: gather paged V + convert + transpose: vt[b][h][d][s]
__global__ void prep_vt(const float* __restrict__ vc, const int* __restrict__ bt,
                        bf16* __restrict__ vt) {
  __shared__ __align__(16) bf16 T[64][136];
  int bid = blockIdx.x;
  int st = bid & 31;
  int h  = (bid >> 5) & 7;
  int b  = bid >> 8;
  int tid = threadIdx.x;
  {
    int s  = tid >> 2;
    int d0 = (tid & 3) * 32;
    int sg = st * 64 + s;
    int pb = bt[b * BPS + (sg >> 5)];
    const float* src = vc + (((size_t)pb * 32 + (sg & 31)) * 8 + h) * 128 + d0;
#pragma unroll
    for (int k = 0; k < 4; ++k) {
      float4 a = *(const float4*)(src + 8 * k);
      float4 c = *(const float4*)(src + 8 * k + 4);
      *(bf16x8*)&T[s][d0 + 8 * k] = cvt8(a, c);
    }
  }
  __syncthreads();
  {
    int d  = tid & 127;
    int g2 = tid >> 7;
    bf16* dst = vt + (((size_t)(b * 8 + h)) * 128 + d) * SKV + st * 64 + g2 * 32;
#pragma unroll
    for (int k = 0; k < 4; ++k) {
      bf16x8 o;
#pragma unroll
      for (int j = 0; j < 8; ++j) o[j] = T[g2 * 32 + k * 8 + j][d];
      *(bf16x8*)(dst + 8 * k) = o;
    }
  }
}

// KV-split flash attention: block = (b,h,32 q rows), 512 threads = 8 waves =
// (4 GQA heads) x (2 kv parities). Wave (g,p) computes kv tiles t==p (mod 2);
// the two dbuf halves are CONCURRENT compute buffers (buf = parity). Each
// 256-thread half stages one tile/superstep (T14 reg prefetch). Per-wave work
// halves; 2 blocks/CU -> 4 waves/SIMD. Partial (m,l,O) merged once at the end
// through LDS (aliased over dead K/V). Swapped QK^T + k-permuted PV (R9 math).
__global__ __launch_bounds__(512, 4)
void attn_split(const float* __restrict__ q, const int* __restrict__ seq_lens,
                const bf16* __restrict__ kb, const bf16* __restrict__ vtb,
                float* __restrict__ out) {
  __shared__ __align__(16) char smem[71680];
  bf16* Kb = (bf16*)smem;               // [2][64][136]
  bf16* Vb = Kb + 2 * 64 * 136;         // [2][128*VST] swizzled

  // bid mapping (R9): complementary qtiles + XCD grouping
  int bid = (int)blockIdx.x;
  int hi  = bid >> 8;
  int u   = bid & 255;
  int xcd = u & 7;
  int k2  = u >> 3;
  int c   = (k2 >> 3) | (xcd << 2);
  int i   = k2 & 7;
  int qt  = hi ? (15 - i) : i;
  int h   = c & 7;
  int b   = c >> 3;
  int lb  = qt * QBL;

  int tid  = (int)threadIdx.x;
  int w    = tid >> 6;       // 0..7
  int g    = w & 3;          // GQA head
  int kvh  = w >> 2;         // kv parity
  int lane = tid & 63;
  int lq   = lane & 15;
  int lg   = lane >> 4;

  int ctx = seq_lens[b] - LQ;
  int nt  = (ctx + lb + QBL + KVB - 1) / KVB;   // >= 25

  const float CEXP = 0.08838834764831843f * 1.44269504088896340f;
  const float TH8  = 8.0f / CEXP;

  int hq = h * GQ + g;
  bf16x8 qf[2][4];
#pragma unroll
  for (int n = 0; n < 2; ++n) {
    const float* qp = q + (((size_t)(b * LQ + lb + n * 16 + lq)) * HQN + hq) * DH + lg * 8;
#pragma unroll
    for (int kk = 0; kk < 4; ++kk) {
      float4 a = *(const float4*)(qp + kk * 32);
      float4 c2 = *(const float4*)(qp + kk * 32 + 4);
      qf[n][kk] = cvt8(a, c2);
    }
  }

  f32x4 accO[2][8];
  f32x4 zero = {0.f, 0.f, 0.f, 0.f};
#pragma unroll
  for (int m = 0; m < 2; ++m)
#pragma unroll
    for (int nd = 0; nd < 8; ++nd) accO[m][nd] = zero;
  float mrun[2] = {-1e30f, -1e30f};
  float lrun[2] = {0.f, 0.f};

  const bf16* kbase = kb  + (size_t)(b * 8 + h) * SKV * DH;
  const bf16* vbase = vtb + (size_t)(b * 8 + h) * DH * SKV;

  // staging geometry: each 256-thread half stages buf[half]
  int half = tid >> 8;
  int tl   = tid & 255;
  int ks_ = tl >> 2, kd0 = (tl & 3) * 32;   // K rows
  int vd_ = tl >> 1, vu  = tl & 1;          // V rows
  int vxw = ((vd_ >> 3) & 3) << 1;

  bf16x8 kpre[4], vpre[4];
  auto ldKV = [&](int t) {
    const bf16* ks = kbase + ((size_t)t * 64 + ks_) * DH + kd0;
#pragma unroll
    for (int k = 0; k < 4; ++k) kpre[k] = *(const bf16x8*)(ks + 8 * k);
    const bf16* vs = vbase + (size_t)vd_ * SKV + t * 64 + vu * 32;
#pragma unroll
    for (int k = 0; k < 4; ++k) vpre[k] = *(const bf16x8*)(vs + 8 * k);
  };
  auto stKV = [&]() {
    bf16* kd = Kb + ((half * 64 + ks_) * 136) + kd0;
#pragma unroll
    for (int k = 0; k < 4; ++k) *(bf16x8*)(kd + 8 * k) = kpre[k];
    bf16* vd = Vb + half * (128 * VST) + vd_ * VST;
#pragma unroll
    for (int k = 0; k < 4; ++k) {
      int gg = (4 * vu + k) ^ vxw;
      *(bf16x8*)(vd + (gg << 3)) = vpre[k];
    }
  };

  auto compute = [&](int t, int bb) {
    const bf16* Kt = Kb + bb * (64 * 136);
    const bf16* Vt = Vb + bb * (128 * VST);
    f32x4 accS[4][2];
#pragma unroll
    for (int m = 0; m < 4; ++m)
#pragma unroll
      for (int n = 0; n < 2; ++n) accS[m][n] = zero;
    __builtin_amdgcn_s_setprio(1);
#pragma unroll
    for (int m = 0; m < 4; ++m) {
      bf16x8 ak[4];
#pragma unroll
      for (int kk = 0; kk < 4; ++kk)
        ak[kk] = *(const bf16x8*)(Kt + (m * 16 + lq) * 136 + kk * 32 + lg * 8);
#pragma unroll
      for (int n = 0; n < 2; ++n)
#pragma unroll
        for (int kk = 0; kk < 4; ++kk)
          accS[m][n] = __builtin_amdgcn_mfma_f32_16x16x32_bf16(ak[kk], qf[n][kk], accS[m][n], 0, 0, 0);
    }
    __builtin_amdgcn_s_setprio(0);

    if (t * KVB + KVB - 1 > ctx + lb) {
#pragma unroll
      for (int m = 0; m < 4; ++m) {
        int sg = t * 64 + m * 16 + lg * 4;
#pragma unroll
        for (int n = 0; n < 2; ++n) {
          int qpos = ctx + lb + n * 16 + lq;
#pragma unroll
          for (int r = 0; r < 4; ++r)
            if (sg + r > qpos) accS[m][n][r] = -1e30f;
        }
      }
    }

#pragma unroll
    for (int n = 0; n < 2; ++n) {
      float mx = accS[0][n][0];
#pragma unroll
      for (int m = 0; m < 4; ++m)
#pragma unroll
        for (int r = 0; r < 4; ++r) mx = fmaxf(mx, accS[m][n][r]);
      mx = fmaxf(mx, __shfl_xor(mx, 16));
      mx = fmaxf(mx, __shfl_xor(mx, 32));
      if (!__all(mx <= mrun[n] + TH8)) {
        float mnew = fmaxf(mrun[n], mx);
        float corr = exp2f((mrun[n] - mnew) * CEXP);
        mrun[n] = mnew;
        lrun[n] *= corr;
        float cb[4];
#pragma unroll
        for (int r = 0; r < 4; ++r) cb[r] = __shfl(corr, lg * 4 + r);
#pragma unroll
        for (int nd = 0; nd < 8; ++nd)
#pragma unroll
          for (int r = 0; r < 4; ++r) accO[n][nd][r] *= cb[r];
      }
      float psum = 0.f;
#pragma unroll
      for (int m = 0; m < 4; ++m)
#pragma unroll
        for (int r = 0; r < 4; ++r) {
          float p = exp2f((accS[m][n][r] - mrun[n]) * CEXP);
          psum += p;
          accS[m][n][r] = p;
        }
      lrun[n] += psum;
    }

    // k-permuted A-fragment (R9): plain cast, zero cross-lane
    bf16x8 ap[2][2];
#pragma unroll
    for (int n = 0; n < 2; ++n)
#pragma unroll
      for (int ks3 = 0; ks3 < 2; ++ks3)
#pragma unroll
        for (int e = 0; e < 4; ++e) {
          ap[n][ks3][e]     = (bf16)accS[2 * ks3][n][e];
          ap[n][ks3][4 + e] = (bf16)accS[2 * ks3 + 1][n][e];
        }

    __builtin_amdgcn_s_setprio(1);
#pragma unroll
    for (int nd = 0; nd < 8; ++nd) {
      int d   = nd * 16 + lq;
      int vxr = ((d >> 3) & 3) << 1;
      int rb  = d * VST + 4 * (lg & 1);
#pragma unroll
      for (int ks3 = 0; ks3 < 2; ++ks3) {
        int g0 = 4 * ks3 + (lg >> 1);
        bf16x4 lo  = *(const bf16x4*)(Vt + rb + ((g0 ^ vxr) << 3));
        bf16x4 hi2 = *(const bf16x4*)(Vt + rb + (((g0 + 2) ^ vxr) << 3));
        bf16x8 bv;
#pragma unroll
        for (int e = 0; e < 4; ++e) { bv[e] = lo[e]; bv[4 + e] = hi2[e]; }
#pragma unroll
        for (int n = 0; n < 2; ++n)
          accO[n][nd] = __builtin_amdgcn_mfma_f32_16x16x32_bf16(ap[n][ks3], bv, accO[n][nd], 0, 0, 0);
      }
    }
    __builtin_amdgcn_s_setprio(0);
  };

  // ---- pipeline: supersteps of 2 tiles (parity -> buffer) ----
  ldKV(half);                 // tiles 0,1
  stKV();
  ldKV(2 + half);             // nt >= 25 always
  __syncthreads();
  for (int s = 0;; ++s) {
    int tc = 2 * s + kvh;
    if (tc < nt) compute(tc, kvh);
    int tn = 2 * (s + 1);
    if (tn >= nt) break;
    __syncthreads();          // all waves done reading both bufs
    if (tn + half < nt) stKV();
    if (tn + 2 + half < nt) ldKV(tn + 2 + half);
    __syncthreads();
  }

  // ---- merge the two kv-parity partials per head ----
#pragma unroll
  for (int n = 0; n < 2; ++n) {
    lrun[n] += __shfl_xor(lrun[n], 16);
    lrun[n] += __shfl_xor(lrun[n], 32);
  }
  __syncthreads();            // K/V LDS is dead; alias merge buffers
  float* Mrg = (float*)smem;              // [4][16][260] interleaved
  float* Mml = Mrg + 4 * 4160;            // [4][2][32]: m then l
  if (kvh == 1) {
    float* base = Mrg + g * 4160;
#pragma unroll
    for (int n = 0; n < 2; ++n)
#pragma unroll
      for (int nd = 0; nd < 8; ++nd)
        *(f32x4*)(base + (n * 8 + nd) * 260 + lane * 4) = accO[n][nd];
    if (lane < 16) {
#pragma unroll
      for (int n = 0; n < 2; ++n) {
        Mml[(g * 2 + n) * 32 + lane]      = mrun[n];
        Mml[(g * 2 + n) * 32 + 16 + lane] = lrun[n];
      }
    }
  }
  __syncthreads();
  if (kvh == 0) {
    float* base = Mrg + g * 4160;
#pragma unroll
    for (int n = 0; n < 2; ++n) {
      float m1 = Mml[(g * 2 + n) * 32 + lq];
      float l1 = Mml[(g * 2 + n) * 32 + 16 + lq];
      float ms = fmaxf(mrun[n], m1);
      float c0 = exp2f((mrun[n] - ms) * CEXP);
      float c1 = exp2f((m1 - ms) * CEXP);
      float li = 1.f / (lrun[n] * c0 + l1 * c1);
      float c0l = c0 * li, c1l = c1 * li;
      float c0b[4], c1b[4];
#pragma unroll
      for (int r = 0; r < 4; ++r) {
        c0b[r] = __shfl(c0l, lg * 4 + r);
        c1b[r] = __shfl(c1l, lg * 4 + r);
      }
      f32x4 o1[8];
#pragma unroll
      for (int nd = 0; nd < 8; ++nd)
        o1[nd] = *(const f32x4*)(base + (n * 8 + nd) * 260 + lane * 4);
#pragma unroll
      for (int r = 0; r < 4; ++r) {
        float* op = out + (((size_t)(b * LQ + lb + n * 16 + lg * 4 + r)) * HQN + hq) * DH + lq;
#pragma unroll
        for (int nd = 0; nd < 8; ++nd)
          op[nd * 16] = accO[n][nd][r] * c0b[r] + o1[nd][r] * c1b[r];
      }
    }
  }
}

// fallback (no workspace): R9's direct-gather single-buffer kernel
__global__ __launch_bounds__(256, 2)
void attn_fb(const float* __restrict__ q, const float* __restrict__ kc,
             const float* __restrict__ vc, const int* __restrict__ bt,
             const int* __restrict__ seq_lens, float* __restrict__ out) {
  __shared__ __align__(16) bf16 Kl[64][136];
  __shared__ __align__(16) bf16 Vl[128 * VST];

  int bid = (int)blockIdx.x;
  int hi  = bid >> 8;
  int u   = bid & 255;
  int xcd = u & 7;
  int k2  = u >> 3;
  int c   = (k2 >> 3) | (xcd << 2);
  int i   = k2 & 7;
  int qt  = hi ? (15 - i) : i;
  int h   = c & 7;
  int b   = c >> 3;
  int lb  = qt * QBL;

  int tid  = (int)threadIdx.x;
  int w    = tid >> 6;
  int lane = tid & 63;
  int lq   = lane & 15;
  int lg   = lane >> 4;

  int ctx = seq_lens[b] - LQ;
  int nt  = (ctx + lb + QBL + KVB - 1) / KVB;

  const float CEXP = 0.08838834764831843f * 1.44269504088896340f;
  const float TH8  = 8.0f / CEXP;

  int hq = h * GQ + w;
  bf16x8 qf[2][4];
#pragma unroll
  for (int n = 0; n < 2; ++n) {
    const float* qp = q + (((size_t)(b * LQ + lb + n * 16 + lq)) * HQN + hq) * DH + lg * 8;
#pragma unroll
    for (int kk = 0; kk < 4; ++kk) {
      float4 a = *(const float4*)(qp + kk * 32);
      float4 c2 = *(const float4*)(qp + kk * 32 + 4);
      qf[n][kk] = cvt8(a, c2);
    }
  }

  f32x4 accO[2][8];
  f32x4 zero = {0.f, 0.f, 0.f, 0.f};
#pragma unroll
  for (int m = 0; m < 2; ++m)
#pragma unroll
    for (int nd = 0; nd < 8; ++nd) accO[m][nd] = zero;
  float mrun[2] = {-1e30f, -1e30f};
  float lrun[2] = {0.f, 0.f};

  const int* btr = bt + b * BPS;

  for (int t = 0; t < nt; ++t) {
    {
      int s  = tid >> 2;
      int d0 = (tid & 3) * 32;
      int pb = btr[t * 2 + (s >> 5)];
      const float* ksrc = kc + (((size_t)pb * 32 + (s & 31)) * 8 + h) * 128 + d0;
#pragma unroll
      for (int k = 0; k < 4; ++k) {
        float4 a = *(const float4*)(ksrc + 8 * k);
        float4 c2 = *(const float4*)(ksrc + 8 * k + 4);
        *(bf16x8*)&Kl[s][d0 + 8 * k] = cvt8(a, c2);
      }
      int d  = tid & 127;
      int sh = tid >> 7;
      int vxf = ((d >> 3) & 3) << 1;
      int pbv = btr[t * 2 + sh];
      const float* vsrc = vc + (((size_t)pbv * 32) * 8 + h) * 128 + d;
#pragma unroll
      for (int k = 0; k < 8; ++k) {
        bf16x4 o;
#pragma unroll
        for (int j = 0; j < 4; ++j) o[j] = (bf16)vsrc[(size_t)(k * 4 + j) * 1024];
        int gg = (4 * sh + (k >> 1)) ^ vxf;
        *(bf16x4*)&Vl[d * VST + (gg << 3) + 4 * (k & 1)] = o;
      }
    }
    __syncthreads();

    f32x4 accS[4][2];
#pragma unroll
    for (int m = 0; m < 4; ++m)
#pragma unroll
      for (int n = 0; n < 2; ++n) accS[m][n] = zero;
#pragma unroll
    for (int m = 0; m < 4; ++m) {
      bf16x8 ak[4];
#pragma unroll
      for (int kk = 0; kk < 4; ++kk)
        ak[kk] = *(const bf16x8*)&Kl[m * 16 + lq][kk * 32 + lg * 8];
#pragma unroll
      for (int n = 0; n < 2; ++n)
#pragma unroll
        for (int kk = 0; kk < 4; ++kk)
          accS[m][n] = __builtin_amdgcn_mfma_f32_16x16x32_bf16(ak[kk], qf[n][kk], accS[m][n], 0, 0, 0);
    }

    if (t * KVB + KVB - 1 > ctx + lb) {
#pragma unroll
      for (int m = 0; m < 4; ++m) {
        int sg = t * 64 + m * 16 + lg * 4;
#pragma unroll
        for (int n = 0; n < 2; ++n) {
          int qpos = ctx + lb + n * 16 + lq;
#pragma unroll
          for (int r = 0; r < 4; ++r)
            if (sg + r > qpos) accS[m][n][r] = -1e30f;
        }
      }
    }

#pragma unroll
    for (int n = 0; n < 2; ++n) {
      float mx = accS[0][n][0];
#pragma unroll
      for (int m = 0; m < 4; ++m)
#pragma unroll
        for (int r = 0; r < 4; ++r) mx = fmaxf(mx, accS[m][n][r]);
      mx = fmaxf(mx, __shfl_xor(mx, 16));
      mx = fmaxf(mx, __shfl_xor(mx, 32));
      if (!__all(mx <= mrun[n] + TH8)) {
        float mnew = fmaxf(mrun[n], mx);
        float corr = exp2f((mrun[n] - mnew) * CEXP);
        mrun[n] = mnew;
        lrun[n] *= corr;
        float cb[4];
#pragma unroll
        for (int r = 0; r < 4; ++r) cb[r] = __shfl(corr, lg * 4 + r);
#pragma unroll
        for (int nd = 0; nd < 8; ++nd)
#pragma unroll
          for (int r = 0; r < 4; ++r) accO[n][nd][r] *= cb[r];
      }
      float psum = 0.f;
#pragma unroll
      for (int m = 0; m < 4; ++m)
#pragma unroll
        for (int r = 0; r < 4; ++r) {
          float p = exp2f((accS[m][n][r] - mrun[n]) * CEXP);
          psum += p;
          accS[m][n][r] = p;
        }
      lrun[n] += psum;
    }

    bf16x8 ap[2][2];
#pragma unroll
    for (int n = 0; n < 2; ++n)
#pragma unroll
      for (int ks3 = 0; ks3 < 2; ++ks3)
#pragma unroll
        for (int e = 0; e < 4; ++e) {
          ap[n][ks3][e]     = (bf16)accS[2 * ks3][n][e];
          ap[n][ks3][4 + e] = (bf16)accS[2 * ks3 + 1][n][e];
        }

#pragma unroll
    for (int nd = 0; nd < 8; ++nd) {
      int d   = nd * 16 + lq;
      int vxr = ((d >> 3) & 3) << 1;
      int rb  = d * VST + 4 * (lg & 1);
#pragma unroll
      for (int ks3 = 0; ks3 < 2; ++ks3) {
        int g0 = 4 * ks3 + (lg >> 1);
        bf16x4 lo  = *(const bf16x4*)&Vl[rb + ((g0 ^ vxr) << 3)];
        bf16x4 hi2 = *(const bf16x4*)&Vl[rb + (((g0 + 2) ^ vxr) << 3)];
        bf16x8 bv;
#pragma unroll
        for (int e = 0; e < 4; ++e) { bv[e] = lo[e]; bv[4 + e] = hi2[e]; }
#pragma unroll
        for (int n = 0; n < 2; ++n)
          accO[n][nd] = __builtin_amdgcn_mfma_f32_16x16x32_bf16(ap[n][ks3], bv, accO[n][nd], 0, 0, 0);
      }
    }
    __syncthreads();
  }

#pragma unroll
  for (int n = 0; n < 2; ++n) {
    lrun[n] += __shfl_xor(lrun[n], 16);
    lrun[n] += __shfl_xor(lrun[n], 32);
    lrun[n] = 1.f / lrun[n];
  }
#pragma unroll
  for (int m2 = 0; m2 < 2; ++m2) {
    float rb[4];
#pragma unroll
    for (int r = 0; r < 4; ++r) rb[r] = __shfl(lrun[m2], lg * 4 + r);
#pragma unroll
    for (int r = 0; r < 4; ++r) {
      float* op = out + (((size_t)(b * LQ + lb + m2 * 16 + lg * 4 + r)) * HQN + hq) * DH + lq;
#pragma unroll
      for (int nd = 0; nd < 8; ++nd) op[nd * 16] = accO[m2][nd][r] * rb[r];
    }
  }
}

extern "C" void kernel_launch(void* const* d_in, const int* in_sizes, int n_in,
                              void* d_out, int out_size, void* d_ws, size_t ws_size,
                              hipStream_t stream) {
  const float* q  = (const float*)d_in[0];
  const float* kc = (const float*)d_in[1];
  const float* vc = (const float*)d_in[2];
  const int* bt   = (const int*)d_in[3];
  const int* sl   = (const int*)d_in[4];
  float* out = (float*)d_out;

  size_t half = (size_t)NSEQ * HKVN * SKV * DH;
  size_t need = 2 * half * sizeof(bf16);
  if (ws_size >= need) {
    bf16* kb = (bf16*)d_ws;
    bf16* vt = kb + half;
    hipLaunchKernelGGL(prep_k, dim3(4096), dim3(256), 0, stream, kc, bt, kb);
    hipLaunchKernelGGL(prep_vt, dim3(1024), dim3(256), 0, stream, vc, bt, vt);
    hipLaunchKernelGGL(attn_split, dim3(512), dim3(512), 0, stream, q, sl, kb, vt, out);
  } else {
    hipLaunchKernelGGL(attn_fb, dim3(512), dim3(256), 0, stream,
                       q, kc, vc, bt, sl, out);
  }
}

// Round 12
// 149.270 us; speedup vs baseline: 3.2799x; 3.2799x over previous
//
#include <hip/hip_runtime.h>
#include <hip/hip_bf16.h>

typedef __bf16 bf16;
typedef __attribute__((ext_vector_type(8))) __bf16 bf16x8;
typedef __attribute__((ext_vector_type(4))) __bf16 bf16x4;
typedef __attribute__((ext_vector_type(4))) float f32x4;

static constexpr int NSEQ = 4;
static constexpr int LQ   = 512;
static constexpr int HQN  = 32;
static constexpr int HKVN = 8;
static constexpr int GQ   = 4;
static constexpr int DH   = 128;
static constexpr int BPS  = 64;     // blocks per sequence (2048/32)
static constexpr int SKV  = 2048;   // max kv length
static constexpr int KVB  = 64;     // kv tile (2 paged blocks)
static constexpr int QBL  = 32;     // l-rows per workgroup (per wave, 1 g head each)
static constexpr int VST  = 72;     // V LDS row stride (elems)

__device__ __forceinline__ bf16x8 cvt8(const float4& a, const float4& b) {
  bf16x8 o;
  o[0] = (bf16)a.x; o[1] = (bf16)a.y; o[2] = (bf16)a.z; o[3] = (bf16)a.w;
  o[4] = (bf16)b.x; o[5] = (bf16)b.y; o[6] = (bf16)b.z; o[7] = (bf16)b.w;
  return o;
}

// prepass 1: gather paged K + convert to bf16: kb[b][h][s][d]
__global__ void prep_k(const float* __restrict__ kc, const int* __restrict__ bt,
                       bf16* __restrict__ kb) {
  int e = (blockIdx.x * 256 + threadIdx.x) * 8;
  int d = e & 127;
  int s = (e >> 7) & 2047;
  int h = (e >> 18) & 7;
  int b = e >> 21;
  int pb = bt[b * BPS + (s >> 5)];
  const float* src = kc + (((size_t)pb * 32 + (s & 31)) * 8 + h) * 128 + d;
  float4 a = *(const float4*)src;
  float4 c = *(const float4*)(src + 4);
  *(bf16x8*)(kb + e) = cvt8(a, c);
}

// prepass 2: gather paged V + convert + transpose: vt[b][h][d][s]
__global__ void prep_vt(const float* __restrict__ vc, const int* __restrict__ bt,
                        bf16* __restrict__ vt) {
  __shared__ __align__(16) bf16 T[64][136];
  int bid = blockIdx.x;
  int st = bid & 31;
  int h  = (bid >> 5) & 7;
  int b  = bid >> 8;
  int tid = threadIdx.x;
  {
    int s  = tid >> 2;
    int d0 = (tid & 3) * 32;
    int sg = st * 64 + s;
    int pb = bt[b * BPS + (sg >> 5)];
    const float* src = vc + (((size_t)pb * 32 + (sg & 31)) * 8 + h) * 128 + d0;
#pragma unroll
    for (int k = 0; k < 4; ++k) {
      float4 a = *(const float4*)(src + 8 * k);
      float4 c = *(const float4*)(src + 8 * k + 4);
      *(bf16x8*)&T[s][d0 + 8 * k] = cvt8(a, c);
    }
  }
  __syncthreads();
  {
    int d  = tid & 127;
    int g2 = tid >> 7;
    bf16* dst = vt + (((size_t)(b * 8 + h)) * 128 + d) * SKV + st * 64 + g2 * 32;
#pragma unroll
    for (int k = 0; k < 4; ++k) {
      bf16x8 o;
#pragma unroll
      for (int j = 0; j < 8; ++j) o[j] = T[g2 * 32 + k * 8 + j][d];
      *(bf16x8*)(dst + 8 * k) = o;
    }
  }
}

// flash attention (R9 structure + critical-path edits): 1 workgroup = (b, h,
// 32 l-rows); wave w = GQA head g = w. Swapped QK^T (A=K, B=Q, 16x16x32) ->
// S^T fragment; softmax in-register (defer-max T13, 4-way psum chains); PV
// via k-PERMUTED 16x16x32 MFMA (A-fragment == accS values, plain cast, zero
// cross-lane). V LDS XOR-swizzled; V reads HOISTED above softmax so their DS
// latency hides under the TRANS chain. Double-buffered K/V, one barrier/tile
// (T14). setprio on MFMA (T5). 2 waves/SIMD -> ~256 VGPR budget, no cap.
template <bool WS>
__global__ __launch_bounds__(256, 2)
void attn_kern(const float* __restrict__ q, const float* __restrict__ kc,
               const float* __restrict__ vc, const int* __restrict__ bt,
               const int* __restrict__ seq_lens, const bf16* __restrict__ kb,
               const bf16* __restrict__ vtb, float* __restrict__ out) {
  __shared__ __align__(16) bf16 Kl[2][64][136];        // [buf][s][d]
  __shared__ __align__(16) bf16 Vl[2][128 * VST];      // [buf][d][s] swizzled

  // bid mapping: bid & bid+256 are complementary qtiles (work sum const),
  // 4 (b,h) combos per XCD residue for L2 locality.
  int bid = (int)blockIdx.x;
  int hi  = bid >> 8;
  int u   = bid & 255;
  int xcd = u & 7;
  int k2  = u >> 3;
  int c   = (k2 >> 3) | (xcd << 2);
  int i   = k2 & 7;
  int qt  = hi ? (15 - i) : i;
  int h   = c & 7;
  int b   = c >> 3;
  int lb  = qt * QBL;

  int tid  = (int)threadIdx.x;
  int w    = tid >> 6;
  int lane = tid & 63;
  int lq   = lane & 15;
  int lg   = lane >> 4;

  int ctx = seq_lens[b] - LQ;
  int nt  = (ctx + lb + QBL + KVB - 1) / KVB;

  const float CEXP = 0.08838834764831843f * 1.44269504088896340f;
  const float TH8  = 8.0f / CEXP;

  // Q fragments (B-operand): lane holds Q[lb + n*16 + lq][kk*32 + lg*8 + j]
  int hq = h * GQ + w;
  bf16x8 qf[2][4];
#pragma unroll
  for (int n = 0; n < 2; ++n) {
    const float* qp = q + (((size_t)(b * LQ + lb + n * 16 + lq)) * HQN + hq) * DH + lg * 8;
#pragma unroll
    for (int kk = 0; kk < 4; ++kk) {
      float4 a = *(const float4*)(qp + kk * 32);
      float4 c2 = *(const float4*)(qp + kk * 32 + 4);
      qf[n][kk] = cvt8(a, c2);
    }
  }

  f32x4 accO[2][8];
  f32x4 zero = {0.f, 0.f, 0.f, 0.f};
#pragma unroll
  for (int m = 0; m < 2; ++m)
#pragma unroll
    for (int nd = 0; nd < 8; ++nd) accO[m][nd] = zero;
  float mrun[2] = {-1e30f, -1e30f};
  float lrun[2] = {0.f, 0.f};

  const int* btr = bt + b * BPS;
  const bf16* kbase = WS ? kb  + (size_t)(b * 8 + h) * SKV * DH : nullptr;
  const bf16* vbase = WS ? vtb + (size_t)(b * 8 + h) * DH * SKV : nullptr;

  // staging geometry
  int ks_ = tid >> 2, kd0 = (tid & 3) * 32;   // K: [s][d] rows
  int vd_ = tid >> 1, vu  = tid & 1;          // V^T: [d][s] rows, col half
  int vxw = ((vd_ >> 3) & 3) << 1;            // write-side granule XOR

  bf16x8 kpre[4], vpre[4];
  auto ldKV = [&](int t) {
    const bf16* ks = kbase + ((size_t)t * 64 + ks_) * DH + kd0;
#pragma unroll
    for (int k = 0; k < 4; ++k) kpre[k] = *(const bf16x8*)(ks + 8 * k);
    const bf16* vs = vbase + (size_t)vd_ * SKV + t * 64 + vu * 32;
#pragma unroll
    for (int k = 0; k < 4; ++k) vpre[k] = *(const bf16x8*)(vs + 8 * k);
  };
  auto stKV = [&](int bb) {
#pragma unroll
    for (int k = 0; k < 4; ++k) *(bf16x8*)&Kl[bb][ks_][kd0 + 8 * k] = kpre[k];
#pragma unroll
    for (int k = 0; k < 4; ++k) {
      int g = (4 * vu + k) ^ vxw;             // swizzled 8-elem granule
      *(bf16x8*)&Vl[bb][vd_ * VST + (g << 3)] = vpre[k];
    }
  };

  auto compute = [&](int t, int bb) {
    // ---- QK^T (swapped): S^T rows s = t*64+m*16+lg*4+r, col q = n*16+lq ----
    f32x4 accS[4][2];
#pragma unroll
    for (int m = 0; m < 4; ++m)
#pragma unroll
      for (int n = 0; n < 2; ++n) accS[m][n] = zero;
    __builtin_amdgcn_s_setprio(1);
#pragma unroll
    for (int m = 0; m < 4; ++m) {
      bf16x8 ak[4];
#pragma unroll
      for (int kk = 0; kk < 4; ++kk)
        ak[kk] = *(const bf16x8*)&Kl[bb][m * 16 + lq][kk * 32 + lg * 8];
#pragma unroll
      for (int n = 0; n < 2; ++n)
#pragma unroll
        for (int kk = 0; kk < 4; ++kk)
          accS[m][n] = __builtin_amdgcn_mfma_f32_16x16x32_bf16(ak[kk], qf[n][kk], accS[m][n], 0, 0, 0);
    }
    __builtin_amdgcn_s_setprio(0);

    // ---- HOISTED V reads: issue now so DS latency hides under softmax ----
    bf16x4 vlo[8][2], vhi[8][2];
#pragma unroll
    for (int nd = 0; nd < 8; ++nd) {
      int d   = nd * 16 + lq;
      int vxr = ((d >> 3) & 3) << 1;
      int rb  = d * VST + 4 * (lg & 1);
#pragma unroll
      for (int ks3 = 0; ks3 < 2; ++ks3) {
        int g0 = 4 * ks3 + (lg >> 1);
        vlo[nd][ks3] = *(const bf16x4*)&Vl[bb][rb + ((g0 ^ vxr) << 3)];
        vhi[nd][ks3] = *(const bf16x4*)&Vl[bb][rb + (((g0 + 2) ^ vxr) << 3)];
      }
    }

    // ---- causal mask (boundary tiles only) ----
    if (t * KVB + KVB - 1 > ctx + lb) {
#pragma unroll
      for (int m = 0; m < 4; ++m) {
        int sg = t * 64 + m * 16 + lg * 4;
#pragma unroll
        for (int n = 0; n < 2; ++n) {
          int qpos = ctx + lb + n * 16 + lq;
#pragma unroll
          for (int r = 0; r < 4; ++r)
            if (sg + r > qpos) accS[m][n][r] = -1e30f;
        }
      }
    }

    // ---- online softmax (per q column = lane&15), defer-max, split psum ----
#pragma unroll
    for (int n = 0; n < 2; ++n) {
      float mx = accS[0][n][0];
#pragma unroll
      for (int m = 0; m < 4; ++m)
#pragma unroll
        for (int r = 0; r < 4; ++r) mx = fmaxf(mx, accS[m][n][r]);
      mx = fmaxf(mx, __shfl_xor(mx, 16));
      mx = fmaxf(mx, __shfl_xor(mx, 32));
      if (!__all(mx <= mrun[n] + TH8)) {
        float mnew = fmaxf(mrun[n], mx);
        float corr = exp2f((mrun[n] - mnew) * CEXP);
        mrun[n] = mnew;
        lrun[n] *= corr;
        float cb[4];
#pragma unroll
        for (int r = 0; r < 4; ++r) cb[r] = __shfl(corr, lg * 4 + r);
#pragma unroll
        for (int nd = 0; nd < 8; ++nd)
#pragma unroll
          for (int r = 0; r < 4; ++r) accO[n][nd][r] *= cb[r];
      }
      float ps[4] = {0.f, 0.f, 0.f, 0.f};   // 4 independent chains (by r)
#pragma unroll
      for (int m = 0; m < 4; ++m)
#pragma unroll
        for (int r = 0; r < 4; ++r) {
          float p = exp2f((accS[m][n][r] - mrun[n]) * CEXP);
          ps[r] += p;
          accS[m][n][r] = p;
        }
      lrun[n] += (ps[0] + ps[1]) + (ps[2] + ps[3]);
    }

    // ---- k-permuted A-fragment: slot j of (n,ks) holds
    // P[s = 32ks + 16(j>>2) + 4lg + (j&3)] = accS[2ks + (j>>2)][n][j&3]. ----
    bf16x8 ap[2][2];
#pragma unroll
    for (int n = 0; n < 2; ++n)
#pragma unroll
      for (int ks3 = 0; ks3 < 2; ++ks3)
#pragma unroll
        for (int e = 0; e < 4; ++e) {
          ap[n][ks3][e]     = (bf16)accS[2 * ks3][n][e];
          ap[n][ks3][4 + e] = (bf16)accS[2 * ks3 + 1][n][e];
        }

    // ---- PV: B slot j of ks = V[s=pi(k)][d], from hoisted V regs ----
    __builtin_amdgcn_s_setprio(1);
#pragma unroll
    for (int nd = 0; nd < 8; ++nd) {
#pragma unroll
      for (int ks3 = 0; ks3 < 2; ++ks3) {
        bf16x8 bv;
#pragma unroll
        for (int e = 0; e < 4; ++e) {
          bv[e]     = vlo[nd][ks3][e];
          bv[4 + e] = vhi[nd][ks3][e];
        }
#pragma unroll
        for (int n = 0; n < 2; ++n)
          accO[n][nd] = __builtin_amdgcn_mfma_f32_16x16x32_bf16(ap[n][ks3], bv, accO[n][nd], 0, 0, 0);
      }
    }
    __builtin_amdgcn_s_setprio(0);
  };

  if (WS) {
    ldKV(0);
    stKV(0);
    if (nt > 1) ldKV(1);
    __syncthreads();
    for (int t = 0; t < nt; ++t) {
      int cur = t & 1;
      if (t + 1 < nt) {
        stKV(cur ^ 1);                 // store t+1 (loads issued last iter)
        if (t + 2 < nt) ldKV(t + 2);
      }
      compute(t, cur);
      __syncthreads();                 // single barrier per tile
    }
  } else {
    for (int t = 0; t < nt; ++t) {
      {
        int s  = tid >> 2;
        int d0 = (tid & 3) * 32;
        int pb = btr[t * 2 + (s >> 5)];
        const float* ksrc = kc + (((size_t)pb * 32 + (s & 31)) * 8 + h) * 128 + d0;
#pragma unroll
        for (int k = 0; k < 4; ++k) {
          float4 a = *(const float4*)(ksrc + 8 * k);
          float4 c2 = *(const float4*)(ksrc + 8 * k + 4);
          *(bf16x8*)&Kl[0][s][d0 + 8 * k] = cvt8(a, c2);
        }
        int d  = tid & 127;
        int sh = tid >> 7;
        int vxf = ((d >> 3) & 3) << 1;
        int pbv = btr[t * 2 + sh];
        const float* vsrc = vc + (((size_t)pbv * 32) * 8 + h) * 128 + d;
#pragma unroll
        for (int k = 0; k < 8; ++k) {
          bf16x4 o;
#pragma unroll
          for (int j = 0; j < 4; ++j) o[j] = (bf16)vsrc[(size_t)(k * 4 + j) * 1024];
          int g = (4 * sh + (k >> 1)) ^ vxf;
          *(bf16x4*)&Vl[0][d * VST + (g << 3) + 4 * (k & 1)] = o;
        }
      }
      __syncthreads();
      compute(t, 0);
      __syncthreads();
    }
  }

  // ---- epilogue: finish row sums, normalize, store f32 ----
#pragma unroll
  for (int n = 0; n < 2; ++n) {
    lrun[n] += __shfl_xor(lrun[n], 16);
    lrun[n] += __shfl_xor(lrun[n], 32);
    lrun[n] = 1.f / lrun[n];
  }
#pragma unroll
  for (int m2 = 0; m2 < 2; ++m2) {
    float rb[4];
#pragma unroll
    for (int r = 0; r < 4; ++r) rb[r] = __shfl(lrun[m2], lg * 4 + r);
#pragma unroll
    for (int r = 0; r < 4; ++r) {
      float* op = out + (((size_t)(b * LQ + lb + m2 * 16 + lg * 4 + r)) * HQN + hq) * DH + lq;
#pragma unroll
      for (int nd = 0; nd < 8; ++nd) op[nd * 16] = accO[m2][nd][r] * rb[r];
    }
  }
}

extern "C" void kernel_launch(void* const* d_in, const int* in_sizes, int n_in,
                              void* d_out, int out_size, void* d_ws, size_t ws_size,
                              hipStream_t stream) {
  const float* q  = (const float*)d_in[0];
  const float* kc = (const float*)d_in[1];
  const float* vc = (const float*)d_in[2];
  const int* bt   = (const int*)d_in[3];
  const int* sl   = (const int*)d_in[4];
  float* out = (float*)d_out;

  size_t half = (size_t)NSEQ * HKVN * SKV * DH;
  size_t need = 2 * half * sizeof(bf16);
  if (ws_size >= need) {
    bf16* kb = (bf16*)d_ws;
    bf16* vt = kb + half;
    hipLaunchKernelGGL(prep_k, dim3(4096), dim3(256), 0, stream, kc, bt, kb);
    hipLaunchKernelGGL(prep_vt, dim3(1024), dim3(256), 0, stream, vc, bt, vt);
    hipLaunchKernelGGL((attn_kern<true>), dim3(512), dim3(256), 0, stream,
                       q, kc, vc, bt, sl, kb, vt, out);
  } else {
    hipLaunchKernelGGL((attn_kern<false>), dim3(512), dim3(256), 0, stream,
                       q, kc, vc, bt, sl, (const bf16*)nullptr, (const bf16*)nullptr, out);
  }
}

// Round 13
// 148.450 us; speedup vs baseline: 3.2980x; 1.0055x over previous
//
#include <hip/hip_runtime.h>
#include <hip/hip_bf16.h>

typedef __bf16 bf16;
typedef __attribute__((ext_vector_type(8))) __bf16 bf16x8;
typedef __attribute__((ext_vector_type(4))) __bf16 bf16x4;
typedef __attribute__((ext_vector_type(4))) float f32x4;

static constexpr int NSEQ = 4;
static constexpr int LQ   = 512;
static constexpr int HQN  = 32;
static constexpr int HKVN = 8;
static constexpr int GQ   = 4;
static constexpr int DH   = 128;
static constexpr int BPS  = 64;     // blocks per sequence (2048/32)
static constexpr int SKV  = 2048;   // max kv length
static constexpr int KVB  = 64;     // kv tile (2 paged blocks)
static constexpr int QBL  = 32;     // l-rows per workgroup
static constexpr int VST  = 72;     // V LDS row stride (elems)

__device__ __forceinline__ bf16x8 cvt8(const float4& a, const float4& b) {
  bf16x8 o;
  o[0] = (bf16)a.x; o[1] = (bf16)a.y; o[2] = (bf16)a.z; o[3] = (bf16)a.w;
  o[4] = (bf16)b.x; o[5] = (bf16)b.y; o[6] = (bf16)b.z; o[7] = (bf16)b.w;
  return o;
}

// prepass 1: gather paged K + convert to bf16: kb[b][h][s][d]
__global__ void prep_k(const float* __restrict__ kc, const int* __restrict__ bt,
                       bf16* __restrict__ kb) {
  int e = (blockIdx.x * 256 + threadIdx.x) * 8;
  int d = e & 127;
  int s = (e >> 7) & 2047;
  int h = (e >> 18) & 7;
  int b = e >> 21;
  int pb = bt[b * BPS + (s >> 5)];
  const float* src = kc + (((size_t)pb * 32 + (s & 31)) * 8 + h) * 128 + d;
  float4 a = *(const float4*)src;
  float4 c = *(const float4*)(src + 4);
  *(bf16x8*)(kb + e) = cvt8(a, c);
}

// prepass 2: gather paged V + convert + transpose: vt[b][h][d][s]
__global__ void prep_vt(const float* __restrict__ vc, const int* __restrict__ bt,
                        bf16* __restrict__ vt) {
  __shared__ __align__(16) bf16 T[64][136];
  int bid = blockIdx.x;
  int st = bid & 31;
  int h  = (bid >> 5) & 7;
  int b  = bid >> 8;
  int tid = threadIdx.x;
  {
    int s  = tid >> 2;
    int d0 = (tid & 3) * 32;
    int sg = st * 64 + s;
    int pb = bt[b * BPS + (sg >> 5)];
    const float* src = vc + (((size_t)pb * 32 + (sg & 31)) * 8 + h) * 128 + d0;
#pragma unroll
    for (int k = 0; k < 4; ++k) {
      float4 a = *(const float4*)(src + 8 * k);
      float4 c = *(const float4*)(src + 8 * k + 4);
      *(bf16x8*)&T[s][d0 + 8 * k] = cvt8(a, c);
    }
  }
  __syncthreads();
  {
    int d  = tid & 127;
    int g2 = tid >> 7;
    bf16* dst = vt + (((size_t)(b * 8 + h)) * 128 + d) * SKV + st * 64 + g2 * 32;
#pragma unroll
    for (int k = 0; k < 4; ++k) {
      bf16x8 o;
#pragma unroll
      for (int j = 0; j < 8; ++j) o[j] = T[g2 * 32 + k * 8 + j][d];
      *(bf16x8*)(dst + 8 * k) = o;
    }
  }
}

// n-split flash attention: block = (b, h, 32 q rows), 512 threads = 8 waves =
// (4 GQA heads g) x (2 q-subtiles nh of 16 rows). Same K/V staging volume per
// block as the 4-wave version (1:1 amortization) but per-wave register state
// and critical path HALVED -> ~115 VGPR -> 16 waves/CU = 4 waves/SIMD. Waves
// own disjoint outputs: no merge. Swapped QK^T + k-permuted PV (R9 math),
// defer-max (T13), XOR-swizzled V LDS (T2), dbuf one-barrier/tile (T14),
// setprio (T5).
__global__ __launch_bounds__(512, 2)
void attn_ns(const float* __restrict__ q, const int* __restrict__ seq_lens,
             const bf16* __restrict__ kb, const bf16* __restrict__ vtb,
             float* __restrict__ out) {
  __shared__ __align__(16) bf16 Kl[2][64][136];        // [buf][s][d]
  __shared__ __align__(16) bf16 Vl[2][128 * VST];      // [buf][d][s] swizzled

  // bid mapping: bid & bid+256 are complementary qtiles (work sum const),
  // 4 (b,h) combos per XCD residue for L2 locality.
  int bid = (int)blockIdx.x;
  int hi  = bid >> 8;
  int u   = bid & 255;
  int xcd = u & 7;
  int k2  = u >> 3;
  int c   = (k2 >> 3) | (xcd << 2);
  int i   = k2 & 7;
  int qt  = hi ? (15 - i) : i;
  int h   = c & 7;
  int b   = c >> 3;
  int lb  = qt * QBL;

  int tid  = (int)threadIdx.x;
  int w    = tid >> 6;       // 0..7
  int g    = w & 3;          // GQA head
  int nh   = w >> 2;         // q-subtile (0: rows 0..15, 1: rows 16..31)
  int lane = tid & 63;
  int lq   = lane & 15;
  int lg   = lane >> 4;

  int ctx = seq_lens[b] - LQ;
  int nt  = (ctx + lb + QBL + KVB - 1) / KVB;
  int qpos = ctx + lb + nh * 16 + lq;

  const float CEXP = 0.08838834764831843f * 1.44269504088896340f;
  const float TH8  = 8.0f / CEXP;

  // Q fragment (B-operand): lane holds Q[lb + nh*16 + lq][kk*32 + lg*8 + j]
  int hq = h * GQ + g;
  bf16x8 qf[4];
  {
    const float* qp = q + (((size_t)(b * LQ + lb + nh * 16 + lq)) * HQN + hq) * DH + lg * 8;
#pragma unroll
    for (int kk = 0; kk < 4; ++kk) {
      float4 a = *(const float4*)(qp + kk * 32);
      float4 c2 = *(const float4*)(qp + kk * 32 + 4);
      qf[kk] = cvt8(a, c2);
    }
  }

  f32x4 accO[8];
  f32x4 zero = {0.f, 0.f, 0.f, 0.f};
#pragma unroll
  for (int nd = 0; nd < 8; ++nd) accO[nd] = zero;
  float mrun = -1e30f, lrun = 0.f;

  const bf16* kbase = kb  + (size_t)(b * 8 + h) * SKV * DH;
  const bf16* vbase = vtb + (size_t)(b * 8 + h) * DH * SKV;

  // staging geometry (512 threads cooperative, same volume as 4-wave version)
  int ks_ = tid >> 3, kd0 = (tid & 7) * 16;   // K: 8 threads/row, 32B each
  int vd_ = tid >> 2, vq  = tid & 3;          // V: 4 threads/row, 32B each
  int vxw = ((vd_ >> 3) & 3) << 1;            // write-side granule XOR

  bf16x8 kpre[2], vpre[2];
  auto ldKV = [&](int t) {
    const bf16* ks = kbase + ((size_t)t * 64 + ks_) * DH + kd0;
    kpre[0] = *(const bf16x8*)ks;
    kpre[1] = *(const bf16x8*)(ks + 8);
    const bf16* vs = vbase + (size_t)vd_ * SKV + t * 64 + vq * 16;
    vpre[0] = *(const bf16x8*)vs;
    vpre[1] = *(const bf16x8*)(vs + 8);
  };
  auto stKV = [&](int bb) {
    *(bf16x8*)&Kl[bb][ks_][kd0]     = kpre[0];
    *(bf16x8*)&Kl[bb][ks_][kd0 + 8] = kpre[1];
#pragma unroll
    for (int k = 0; k < 2; ++k) {
      int gg = (2 * vq + k) ^ vxw;            // swizzled 8-elem granule
      *(bf16x8*)&Vl[bb][vd_ * VST + (gg << 3)] = vpre[k];
    }
  };

  auto compute = [&](int t, int bb) {
    // ---- QK^T (swapped): S^T rows s = t*64+m*16+lg*4+r, col q = nh*16+lq ----
    f32x4 accS[4];
#pragma unroll
    for (int m = 0; m < 4; ++m) accS[m] = zero;
    __builtin_amdgcn_s_setprio(1);
#pragma unroll
    for (int m = 0; m < 4; ++m) {
#pragma unroll
      for (int kk = 0; kk < 4; ++kk) {
        bf16x8 ak = *(const bf16x8*)&Kl[bb][m * 16 + lq][kk * 32 + lg * 8];
        accS[m] = __builtin_amdgcn_mfma_f32_16x16x32_bf16(ak, qf[kk], accS[m], 0, 0, 0);
      }
    }
    __builtin_amdgcn_s_setprio(0);

    // ---- causal mask (boundary tiles only) ----
    if (t * KVB + KVB - 1 > ctx + lb) {
#pragma unroll
      for (int m = 0; m < 4; ++m) {
        int sg = t * 64 + m * 16 + lg * 4;
#pragma unroll
        for (int r = 0; r < 4; ++r)
          if (sg + r > qpos) accS[m][r] = -1e30f;
      }
    }

    // ---- online softmax (per q column = lane&15), defer-max, split psum ----
    {
      float mx = accS[0][0];
#pragma unroll
      for (int m = 0; m < 4; ++m)
#pragma unroll
        for (int r = 0; r < 4; ++r) mx = fmaxf(mx, accS[m][r]);
      mx = fmaxf(mx, __shfl_xor(mx, 16));
      mx = fmaxf(mx, __shfl_xor(mx, 32));
      if (!__all(mx <= mrun + TH8)) {
        float mnew = fmaxf(mrun, mx);
        float corr = exp2f((mrun - mnew) * CEXP);
        mrun = mnew;
        lrun *= corr;
        float cb[4];
#pragma unroll
        for (int r = 0; r < 4; ++r) cb[r] = __shfl(corr, lg * 4 + r);
#pragma unroll
        for (int nd = 0; nd < 8; ++nd)
#pragma unroll
          for (int r = 0; r < 4; ++r) accO[nd][r] *= cb[r];
      }
      float ps[4] = {0.f, 0.f, 0.f, 0.f};
#pragma unroll
      for (int m = 0; m < 4; ++m)
#pragma unroll
        for (int r = 0; r < 4; ++r) {
          float p = exp2f((accS[m][r] - mrun) * CEXP);
          ps[r] += p;
          accS[m][r] = p;
        }
      lrun += (ps[0] + ps[1]) + (ps[2] + ps[3]);
    }

    // ---- k-permuted A-fragment: slot j of ks holds
    // P[s = 32ks + 16(j>>2) + 4lg + (j&3)] = accS[2ks + (j>>2)][j&3]. ----
    bf16x8 ap[2];
#pragma unroll
    for (int ks3 = 0; ks3 < 2; ++ks3)
#pragma unroll
      for (int e = 0; e < 4; ++e) {
        ap[ks3][e]     = (bf16)accS[2 * ks3][e];
        ap[ks3][4 + e] = (bf16)accS[2 * ks3 + 1][e];
      }

    // ---- PV: B slot j of ks = V[s=pi(k)][d], from swizzled Vl ----
    __builtin_amdgcn_s_setprio(1);
#pragma unroll
    for (int nd = 0; nd < 8; ++nd) {
      int d   = nd * 16 + lq;
      int vxr = ((d >> 3) & 3) << 1;
      int rb  = d * VST + 4 * (lg & 1);
#pragma unroll
      for (int ks3 = 0; ks3 < 2; ++ks3) {
        int g0 = 4 * ks3 + (lg >> 1);
        bf16x4 lo  = *(const bf16x4*)&Vl[bb][rb + ((g0 ^ vxr) << 3)];
        bf16x4 hi2 = *(const bf16x4*)&Vl[bb][rb + (((g0 + 2) ^ vxr) << 3)];
        bf16x8 bv;
#pragma unroll
        for (int e = 0; e < 4; ++e) { bv[e] = lo[e]; bv[4 + e] = hi2[e]; }
        accO[nd] = __builtin_amdgcn_mfma_f32_16x16x32_bf16(ap[ks3], bv, accO[nd], 0, 0, 0);
      }
    }
    __builtin_amdgcn_s_setprio(0);
  };

  // ---- pipeline: dbuf, one barrier per tile (T14) ----
  ldKV(0);
  stKV(0);
  if (nt > 1) ldKV(1);
  __syncthreads();
  for (int t = 0; t < nt; ++t) {
    int cur = t & 1;
    if (t + 1 < nt) {
      stKV(cur ^ 1);                 // store t+1 (loads issued last iter)
      if (t + 2 < nt) ldKV(t + 2);
    }
    compute(t, cur);
    __syncthreads();                 // single barrier per tile
  }

  // ---- epilogue: finish row sums, normalize, store f32 ----
  lrun += __shfl_xor(lrun, 16);
  lrun += __shfl_xor(lrun, 32);
  float linv = 1.f / lrun;
  float rb[4];
#pragma unroll
  for (int r = 0; r < 4; ++r) rb[r] = __shfl(linv, lg * 4 + r);
#pragma unroll
  for (int r = 0; r < 4; ++r) {
    float* op = out + (((size_t)(b * LQ + lb + nh * 16 + lg * 4 + r)) * HQN + hq) * DH + lq;
#pragma unroll
    for (int nd = 0; nd < 8; ++nd) op[nd * 16] = accO[nd][r] * rb[r];
  }
}

// fallback (no workspace): R9-equivalent direct-gather single-buffer kernel
__global__ __launch_bounds__(256, 2)
void attn_fb(const float* __restrict__ q, const float* __restrict__ kc,
             const float* __restrict__ vc, const int* __restrict__ bt,
             const int* __restrict__ seq_lens, float* __restrict__ out) {
  __shared__ __align__(16) bf16 Kl[64][136];
  __shared__ __align__(16) bf16 Vl[128 * VST];

  int bid = (int)blockIdx.x;
  int hi  = bid >> 8;
  int u   = bid & 255;
  int xcd = u & 7;
  int k2  = u >> 3;
  int c   = (k2 >> 3) | (xcd << 2);
  int i   = k2 & 7;
  int qt  = hi ? (15 - i) : i;
  int h   = c & 7;
  int b   = c >> 3;
  int lb  = qt * QBL;

  int tid  = (int)threadIdx.x;
  int w    = tid >> 6;
  int lane = tid & 63;
  int lq   = lane & 15;
  int lg   = lane >> 4;

  int ctx = seq_lens[b] - LQ;
  int nt  = (ctx + lb + QBL + KVB - 1) / KVB;

  const float CEXP = 0.08838834764831843f * 1.44269504088896340f;
  const float TH8  = 8.0f / CEXP;

  int hq = h * GQ + w;
  bf16x8 qf[2][4];
#pragma unroll
  for (int n = 0; n < 2; ++n) {
    const float* qp = q + (((size_t)(b * LQ + lb + n * 16 + lq)) * HQN + hq) * DH + lg * 8;
#pragma unroll
    for (int kk = 0; kk < 4; ++kk) {
      float4 a = *(const float4*)(qp + kk * 32);
      float4 c2 = *(const float4*)(qp + kk * 32 + 4);
      qf[n][kk] = cvt8(a, c2);
    }
  }

  f32x4 accO[2][8];
  f32x4 zero = {0.f, 0.f, 0.f, 0.f};
#pragma unroll
  for (int m = 0; m < 2; ++m)
#pragma unroll
    for (int nd = 0; nd < 8; ++nd) accO[m][nd] = zero;
  float mrun[2] = {-1e30f, -1e30f};
  float lrun[2] = {0.f, 0.f};

  const int* btr = bt + b * BPS;

  for (int t = 0; t < nt; ++t) {
    {
      int s  = tid >> 2;
      int d0 = (tid & 3) * 32;
      int pb = btr[t * 2 + (s >> 5)];
      const float* ksrc = kc + (((size_t)pb * 32 + (s & 31)) * 8 + h) * 128 + d0;
#pragma unroll
      for (int k = 0; k < 4; ++k) {
        float4 a = *(const float4*)(ksrc + 8 * k);
        float4 c2 = *(const float4*)(ksrc + 8 * k + 4);
        *(bf16x8*)&Kl[s][d0 + 8 * k] = cvt8(a, c2);
      }
      int d  = tid & 127;
      int sh = tid >> 7;
      int vxf = ((d >> 3) & 3) << 1;
      int pbv = btr[t * 2 + sh];
      const float* vsrc = vc + (((size_t)pbv * 32) * 8 + h) * 128 + d;
#pragma unroll
      for (int k = 0; k < 8; ++k) {
        bf16x4 o;
#pragma unroll
        for (int j = 0; j < 4; ++j) o[j] = (bf16)vsrc[(size_t)(k * 4 + j) * 1024];
        int gg = (4 * sh + (k >> 1)) ^ vxf;
        *(bf16x4*)&Vl[d * VST + (gg << 3) + 4 * (k & 1)] = o;
      }
    }
    __syncthreads();

    f32x4 accS[4][2];
#pragma unroll
    for (int m = 0; m < 4; ++m)
#pragma unroll
      for (int n = 0; n < 2; ++n) accS[m][n] = zero;
#pragma unroll
    for (int m = 0; m < 4; ++m) {
      bf16x8 ak[4];
#pragma unroll
      for (int kk = 0; kk < 4; ++kk)
        ak[kk] = *(const bf16x8*)&Kl[m * 16 + lq][kk * 32 + lg * 8];
#pragma unroll
      for (int n = 0; n < 2; ++n)
#pragma unroll
        for (int kk = 0; kk < 4; ++kk)
          accS[m][n] = __builtin_amdgcn_mfma_f32_16x16x32_bf16(ak[kk], qf[n][kk], accS[m][n], 0, 0, 0);
    }

    if (t * KVB + KVB - 1 > ctx + lb) {
#pragma unroll
      for (int m = 0; m < 4; ++m) {
        int sg = t * 64 + m * 16 + lg * 4;
#pragma unroll
        for (int n = 0; n < 2; ++n) {
          int qpos = ctx + lb + n * 16 + lq;
#pragma unroll
          for (int r = 0; r < 4; ++r)
            if (sg + r > qpos) accS[m][n][r] = -1e30f;
        }
      }
    }

#pragma unroll
    for (int n = 0; n < 2; ++n) {
      float mx = accS[0][n][0];
#pragma unroll
      for (int m = 0; m < 4; ++m)
#pragma unroll
        for (int r = 0; r < 4; ++r) mx = fmaxf(mx, accS[m][n][r]);
      mx = fmaxf(mx, __shfl_xor(mx, 16));
      mx = fmaxf(mx, __shfl_xor(mx, 32));
      if (!__all(mx <= mrun[n] + TH8)) {
        float mnew = fmaxf(mrun[n], mx);
        float corr = exp2f((mrun[n] - mnew) * CEXP);
        mrun[n] = mnew;
        lrun[n] *= corr;
        float cb[4];
#pragma unroll
        for (int r = 0; r < 4; ++r) cb[r] = __shfl(corr, lg * 4 + r);
#pragma unroll
        for (int nd = 0; nd < 8; ++nd)
#pragma unroll
          for (int r = 0; r < 4; ++r) accO[n][nd][r] *= cb[r];
      }
      float psum = 0.f;
#pragma unroll
      for (int m = 0; m < 4; ++m)
#pragma unroll
        for (int r = 0; r < 4; ++r) {
          float p = exp2f((accS[m][n][r] - mrun[n]) * CEXP);
          psum += p;
          accS[m][n][r] = p;
        }
      lrun[n] += psum;
    }

    bf16x8 ap[2][2];
#pragma unroll
    for (int n = 0; n < 2; ++n)
#pragma unroll
      for (int ks3 = 0; ks3 < 2; ++ks3)
#pragma unroll
        for (int e = 0; e < 4; ++e) {
          ap[n][ks3][e]     = (bf16)accS[2 * ks3][n][e];
          ap[n][ks3][4 + e] = (bf16)accS[2 * ks3 + 1][n][e];
        }

#pragma unroll
    for (int nd = 0; nd < 8; ++nd) {
      int d   = nd * 16 + lq;
      int vxr = ((d >> 3) & 3) << 1;
      int rb  = d * VST + 4 * (lg & 1);
#pragma unroll
      for (int ks3 = 0; ks3 < 2; ++ks3) {
        int g0 = 4 * ks3 + (lg >> 1);
        bf16x4 lo  = *(const bf16x4*)&Vl[rb + ((g0 ^ vxr) << 3)];
        bf16x4 hi2 = *(const bf16x4*)&Vl[rb + (((g0 + 2) ^ vxr) << 3)];
        bf16x8 bv;
#pragma unroll
        for (int e = 0; e < 4; ++e) { bv[e] = lo[e]; bv[4 + e] = hi2[e]; }
#pragma unroll
        for (int n = 0; n < 2; ++n)
          accO[n][nd] = __builtin_amdgcn_mfma_f32_16x16x32_bf16(ap[n][ks3], bv, accO[n][nd], 0, 0, 0);
      }
    }
    __syncthreads();
  }

#pragma unroll
  for (int n = 0; n < 2; ++n) {
    lrun[n] += __shfl_xor(lrun[n], 16);
    lrun[n] += __shfl_xor(lrun[n], 32);
    lrun[n] = 1.f / lrun[n];
  }
#pragma unroll
  for (int m2 = 0; m2 < 2; ++m2) {
    float rb[4];
#pragma unroll
    for (int r = 0; r < 4; ++r) rb[r] = __shfl(lrun[m2], lg * 4 + r);
#pragma unroll
    for (int r = 0; r < 4; ++r) {
      float* op = out + (((size_t)(b * LQ + lb + m2 * 16 + lg * 4 + r)) * HQN + hq) * DH + lq;
#pragma unroll
      for (int nd = 0; nd < 8; ++nd) op[nd * 16] = accO[m2][nd][r] * rb[r];
    }
  }
}

extern "C" void kernel_launch(void* const* d_in, const int* in_sizes, int n_in,
                              void* d_out, int out_size, void* d_ws, size_t ws_size,
                              hipStream_t stream) {
  const float* q  = (const float*)d_in[0];
  const float* kc = (const float*)d_in[1];
  const float* vc = (const float*)d_in[2];
  const int* bt   = (const int*)d_in[3];
  const int* sl   = (const int*)d_in[4];
  float* out = (float*)d_out;

  size_t half = (size_t)NSEQ * HKVN * SKV * DH;
  size_t need = 2 * half * sizeof(bf16);
  if (ws_size >= need) {
    bf16* kb = (bf16*)d_ws;
    bf16* vt = kb + half;
    hipLaunchKernelGGL(prep_k, dim3(4096), dim3(256), 0, stream, kc, bt, kb);
    hipLaunchKernelGGL(prep_vt, dim3(1024), dim3(256), 0, stream, vc, bt, vt);
    hipLaunchKernelGGL(attn_ns, dim3(512), dim3(512), 0, stream, q, sl, kb, vt, out);
  } else {
    hipLaunchKernelGGL(attn_fb, dim3(512), dim3(256), 0, stream,
                       q, kc, vc, bt, sl, out);
  }
}

// Round 14
// 122.060 us; speedup vs baseline: 4.0111x; 1.2162x over previous
//
#include <hip/hip_runtime.h>
#include <hip/hip_bf16.h>

typedef __bf16 bf16;
typedef __attribute__((ext_vector_type(8))) __bf16 bf16x8;
typedef __attribute__((ext_vector_type(4))) __bf16 bf16x4;
typedef __attribute__((ext_vector_type(4))) float f32x4;

static constexpr int NSEQ = 4;
static constexpr int LQ   = 512;
static constexpr int HQN  = 32;
static constexpr int HKVN = 8;
static constexpr int GQ   = 4;
static constexpr int DH   = 128;
static constexpr int BPS  = 64;     // blocks per sequence (2048/32)
static constexpr int SKV  = 2048;   // max kv length
static constexpr int KVB  = 64;     // kv tile (2 paged blocks)
static constexpr int QBL  = 32;     // l-rows per workgroup (per wave, 1 g head each)
static constexpr int VST  = 72;     // V LDS row stride (elems)

__device__ __forceinline__ bf16x8 cvt8(const float4& a, const float4& b) {
  bf16x8 o;
  o[0] = (bf16)a.x; o[1] = (bf16)a.y; o[2] = (bf16)a.z; o[3] = (bf16)a.w;
  o[4] = (bf16)b.x; o[5] = (bf16)b.y; o[6] = (bf16)b.z; o[7] = (bf16)b.w;
  return o;
}

// prepass 1: gather paged K + convert to bf16: kb[b][h][s][d]
__global__ void prep_k(const float* __restrict__ kc, const int* __restrict__ bt,
                       bf16* __restrict__ kb) {
  int e = (blockIdx.x * 256 + threadIdx.x) * 8;
  int d = e & 127;
  int s = (e >> 7) & 2047;
  int h = (e >> 18) & 7;
  int b = e >> 21;
  int pb = bt[b * BPS + (s >> 5)];
  const float* src = kc + (((size_t)pb * 32 + (s & 31)) * 8 + h) * 128 + d;
  float4 a = *(const float4*)src;
  float4 c = *(const float4*)(src + 4);
  *(bf16x8*)(kb + e) = cvt8(a, c);
}

// prepass 2: gather paged V + convert + transpose: vt[b][h][d][s]
__global__ void prep_vt(const float* __restrict__ vc, const int* __restrict__ bt,
                        bf16* __restrict__ vt) {
  __shared__ __align__(16) bf16 T[64][136];
  int bid = blockIdx.x;
  int st = bid & 31;
  int h  = (bid >> 5) & 7;
  int b  = bid >> 8;
  int tid = threadIdx.x;
  {
    int s  = tid >> 2;
    int d0 = (tid & 3) * 32;
    int sg = st * 64 + s;
    int pb = bt[b * BPS + (sg >> 5)];
    const float* src = vc + (((size_t)pb * 32 + (sg & 31)) * 8 + h) * 128 + d0;
#pragma unroll
    for (int k = 0; k < 4; ++k) {
      float4 a = *(const float4*)(src + 8 * k);
      float4 c = *(const float4*)(src + 8 * k + 4);
      *(bf16x8*)&T[s][d0 + 8 * k] = cvt8(a, c);
    }
  }
  __syncthreads();
  {
    int d  = tid & 127;
    int g2 = tid >> 7;
    bf16* dst = vt + (((size_t)(b * 8 + h)) * 128 + d) * SKV + st * 64 + g2 * 32;
#pragma unroll
    for (int k = 0; k < 4; ++k) {
      bf16x8 o;
#pragma unroll
      for (int j = 0; j < 8; ++j) o[j] = T[g2 * 32 + k * 8 + j][d];
      *(bf16x8*)(dst + 8 * k) = o;
    }
  }
}

// flash attention (R9 structure, setprio removed per m190 lockstep evidence):
// 1 workgroup = (b, h, 32 l-rows); wave w = GQA head g = w. Swapped QK^T
// (A=K, B=Q, 16x16x32) -> S^T fragment; softmax in-register (defer-max T13);
// PV via k-PERMUTED 16x16x32 MFMA: the same k-slot permutation pi on A and B
// leaves the contraction invariant; pi is picked so the A-fragment equals the
// values already in accS (plain f32->bf16 cast, zero cross-lane). V LDS uses
// an XOR granule swizzle (T2). Double-buffered K/V, one barrier/tile (T14).
// 2 waves/SIMD is the measured stable operating point (R8/R11/R12/R13 all
// regressed trying to exceed it: staging-doubling / spill / spill / conflicts).
template <bool WS>
__global__ __launch_bounds__(256, 2)
void attn_kern(const float* __restrict__ q, const float* __restrict__ kc,
               const float* __restrict__ vc, const int* __restrict__ bt,
               const int* __restrict__ seq_lens, const bf16* __restrict__ kb,
               const bf16* __restrict__ vtb, float* __restrict__ out) {
  __shared__ __align__(16) bf16 Kl[2][64][136];        // [buf][s][d]
  __shared__ __align__(16) bf16 Vl[2][128 * VST];      // [buf][d][s] swizzled

  // bid mapping: bid & bid+256 are complementary qtiles (work sum const),
  // 4 (b,h) combos per XCD residue for L2 locality.
  int bid = (int)blockIdx.x;
  int hi  = bid >> 8;
  int u   = bid & 255;
  int xcd = u & 7;
  int k2  = u >> 3;
  int c   = (k2 >> 3) | (xcd << 2);
  int i   = k2 & 7;
  int qt  = hi ? (15 - i) : i;
  int h   = c & 7;
  int b   = c >> 3;
  int lb  = qt * QBL;

  int tid  = (int)threadIdx.x;
  int w    = tid >> 6;
  int lane = tid & 63;
  int lq   = lane & 15;
  int lg   = lane >> 4;

  int ctx = seq_lens[b] - LQ;
  int nt  = (ctx + lb + QBL + KVB - 1) / KVB;

  const float CEXP = 0.08838834764831843f * 1.44269504088896340f;
  const float TH8  = 8.0f / CEXP;

  // Q fragments (B-operand): lane holds Q[lb + n*16 + lq][kk*32 + lg*8 + j]
  int hq = h * GQ + w;
  bf16x8 qf[2][4];
#pragma unroll
  for (int n = 0; n < 2; ++n) {
    const float* qp = q + (((size_t)(b * LQ + lb + n * 16 + lq)) * HQN + hq) * DH + lg * 8;
#pragma unroll
    for (int kk = 0; kk < 4; ++kk) {
      float4 a = *(const float4*)(qp + kk * 32);
      float4 c2 = *(const float4*)(qp + kk * 32 + 4);
      qf[n][kk] = cvt8(a, c2);
    }
  }

  f32x4 accO[2][8];
  f32x4 zero = {0.f, 0.f, 0.f, 0.f};
#pragma unroll
  for (int m = 0; m < 2; ++m)
#pragma unroll
    for (int nd = 0; nd < 8; ++nd) accO[m][nd] = zero;
  float mrun[2] = {-1e30f, -1e30f};
  float lrun[2] = {0.f, 0.f};

  const int* btr = bt + b * BPS;
  const bf16* kbase = WS ? kb  + (size_t)(b * 8 + h) * SKV * DH : nullptr;
  const bf16* vbase = WS ? vtb + (size_t)(b * 8 + h) * DH * SKV : nullptr;

  // staging geometry
  int ks_ = tid >> 2, kd0 = (tid & 3) * 32;   // K: [s][d] rows
  int vd_ = tid >> 1, vu  = tid & 1;          // V^T: [d][s] rows, col half
  int vxw = ((vd_ >> 3) & 3) << 1;            // write-side granule XOR

  bf16x8 kpre[4], vpre[4];
  auto ldKV = [&](int t) {
    const bf16* ks = kbase + ((size_t)t * 64 + ks_) * DH + kd0;
#pragma unroll
    for (int k = 0; k < 4; ++k) kpre[k] = *(const bf16x8*)(ks + 8 * k);
    const bf16* vs = vbase + (size_t)vd_ * SKV + t * 64 + vu * 32;
#pragma unroll
    for (int k = 0; k < 4; ++k) vpre[k] = *(const bf16x8*)(vs + 8 * k);
  };
  auto stKV = [&](int bb) {
#pragma unroll
    for (int k = 0; k < 4; ++k) *(bf16x8*)&Kl[bb][ks_][kd0 + 8 * k] = kpre[k];
#pragma unroll
    for (int k = 0; k < 4; ++k) {
      int g = (4 * vu + k) ^ vxw;             // swizzled 8-elem granule
      *(bf16x8*)&Vl[bb][vd_ * VST + (g << 3)] = vpre[k];
    }
  };

  auto compute = [&](int t, int bb) {
    // ---- QK^T (swapped): S^T rows s = t*64+m*16+lg*4+r, col q = n*16+lq ----
    f32x4 accS[4][2];
#pragma unroll
    for (int m = 0; m < 4; ++m)
#pragma unroll
      for (int n = 0; n < 2; ++n) accS[m][n] = zero;
#pragma unroll
    for (int m = 0; m < 4; ++m) {
      bf16x8 ak[4];
#pragma unroll
      for (int kk = 0; kk < 4; ++kk)
        ak[kk] = *(const bf16x8*)&Kl[bb][m * 16 + lq][kk * 32 + lg * 8];
#pragma unroll
      for (int n = 0; n < 2; ++n)
#pragma unroll
        for (int kk = 0; kk < 4; ++kk)
          accS[m][n] = __builtin_amdgcn_mfma_f32_16x16x32_bf16(ak[kk], qf[n][kk], accS[m][n], 0, 0, 0);
    }

    // ---- causal mask (boundary tiles only) ----
    if (t * KVB + KVB - 1 > ctx + lb) {
#pragma unroll
      for (int m = 0; m < 4; ++m) {
        int sg = t * 64 + m * 16 + lg * 4;
#pragma unroll
        for (int n = 0; n < 2; ++n) {
          int qpos = ctx + lb + n * 16 + lq;
#pragma unroll
          for (int r = 0; r < 4; ++r)
            if (sg + r > qpos) accS[m][n][r] = -1e30f;
        }
      }
    }

    // ---- online softmax (per q column = lane&15), defer-max ----
#pragma unroll
    for (int n = 0; n < 2; ++n) {
      float mx = accS[0][n][0];
#pragma unroll
      for (int m = 0; m < 4; ++m)
#pragma unroll
        for (int r = 0; r < 4; ++r) mx = fmaxf(mx, accS[m][n][r]);
      mx = fmaxf(mx, __shfl_xor(mx, 16));
      mx = fmaxf(mx, __shfl_xor(mx, 32));
      if (!__all(mx <= mrun[n] + TH8)) {
        float mnew = fmaxf(mrun[n], mx);
        float corr = exp2f((mrun[n] - mnew) * CEXP);
        mrun[n] = mnew;
        lrun[n] *= corr;
        float cb[4];
#pragma unroll
        for (int r = 0; r < 4; ++r) cb[r] = __shfl(corr, lg * 4 + r);
#pragma unroll
        for (int nd = 0; nd < 8; ++nd)
#pragma unroll
          for (int r = 0; r < 4; ++r) accO[n][nd][r] *= cb[r];
      }
      float psum = 0.f;
#pragma unroll
      for (int m = 0; m < 4; ++m)
#pragma unroll
        for (int r = 0; r < 4; ++r) {
          float p = exp2f((accS[m][n][r] - mrun[n]) * CEXP);
          psum += p;
          accS[m][n][r] = p;
        }
      lrun[n] += psum;
    }

    // ---- k-permuted A-fragment: slot j of (n,ks) holds
    // P[s = 32ks + 16(j>>2) + 4lg + (j&3)] = accS[2ks + (j>>2)][n][j&3]. ----
    bf16x8 ap[2][2];
#pragma unroll
    for (int n = 0; n < 2; ++n)
#pragma unroll
      for (int ks3 = 0; ks3 < 2; ++ks3) {
#pragma unroll
        for (int e = 0; e < 4; ++e) {
          ap[n][ks3][e]     = (bf16)accS[2 * ks3][n][e];
          ap[n][ks3][4 + e] = (bf16)accS[2 * ks3 + 1][n][e];
        }
      }

    // ---- PV: B slot j of ks = V[s=pi(k)][d], read from swizzled Vl ----
#pragma unroll
    for (int nd = 0; nd < 8; ++nd) {
      int d   = nd * 16 + lq;
      int vxr = ((d >> 3) & 3) << 1;
      int rb  = d * VST + 4 * (lg & 1);
#pragma unroll
      for (int ks3 = 0; ks3 < 2; ++ks3) {
        int g0 = 4 * ks3 + (lg >> 1);
        bf16x4 lo = *(const bf16x4*)&Vl[bb][rb + ((g0 ^ vxr) << 3)];
        bf16x4 hi2 = *(const bf16x4*)&Vl[bb][rb + (((g0 + 2) ^ vxr) << 3)];
        bf16x8 bv;
#pragma unroll
        for (int e = 0; e < 4; ++e) { bv[e] = lo[e]; bv[4 + e] = hi2[e]; }
#pragma unroll
        for (int n = 0; n < 2; ++n)
          accO[n][nd] = __builtin_amdgcn_mfma_f32_16x16x32_bf16(ap[n][ks3], bv, accO[n][nd], 0, 0, 0);
      }
    }
  };

  if (WS) {
    ldKV(0);
    stKV(0);
    if (nt > 1) ldKV(1);
    __syncthreads();
    for (int t = 0; t < nt; ++t) {
      int cur = t & 1;
      if (t + 1 < nt) {
        stKV(cur ^ 1);                 // store t+1 (loads issued last iter)
        if (t + 2 < nt) ldKV(t + 2);
      }
      compute(t, cur);
      __syncthreads();                 // single barrier per tile
    }
  } else {
    for (int t = 0; t < nt; ++t) {
      {
        int s  = tid >> 2;
        int d0 = (tid & 3) * 32;
        int pb = btr[t * 2 + (s >> 5)];
        const float* ksrc = kc + (((size_t)pb * 32 + (s & 31)) * 8 + h) * 128 + d0;
#pragma unroll
        for (int k = 0; k < 4; ++k) {
          float4 a = *(const float4*)(ksrc + 8 * k);
          float4 c2 = *(const float4*)(ksrc + 8 * k + 4);
          *(bf16x8*)&Kl[0][s][d0 + 8 * k] = cvt8(a, c2);
        }
        int d  = tid & 127;
        int sh = tid >> 7;
        int vxf = ((d >> 3) & 3) << 1;
        int pbv = btr[t * 2 + sh];
        const float* vsrc = vc + (((size_t)pbv * 32) * 8 + h) * 128 + d;
#pragma unroll
        for (int k = 0; k < 8; ++k) {
          bf16x4 o;
#pragma unroll
          for (int j = 0; j < 4; ++j) o[j] = (bf16)vsrc[(size_t)(k * 4 + j) * 1024];
          int g = (4 * sh + (k >> 1)) ^ vxf;
          *(bf16x4*)&Vl[0][d * VST + (g << 3) + 4 * (k & 1)] = o;
        }
      }
      __syncthreads();
      compute(t, 0);
      __syncthreads();
    }
  }

  // ---- epilogue: finish row sums, normalize, store f32 ----
#pragma unroll
  for (int n = 0; n < 2; ++n) {
    lrun[n] += __shfl_xor(lrun[n], 16);
    lrun[n] += __shfl_xor(lrun[n], 32);
    lrun[n] = 1.f / lrun[n];
  }
#pragma unroll
  for (int m2 = 0; m2 < 2; ++m2) {
    float rb[4];
#pragma unroll
    for (int r = 0; r < 4; ++r) rb[r] = __shfl(lrun[m2], lg * 4 + r);
#pragma unroll
    for (int r = 0; r < 4; ++r) {
      float* op = out + (((size_t)(b * LQ + lb + m2 * 16 + lg * 4 + r)) * HQN + hq) * DH + lq;
#pragma unroll
      for (int nd = 0; nd < 8; ++nd) op[nd * 16] = accO[m2][nd][r] * rb[r];
    }
  }
}

extern "C" void kernel_launch(void* const* d_in, const int* in_sizes, int n_in,
                              void* d_out, int out_size, void* d_ws, size_t ws_size,
                              hipStream_t stream) {
  const float* q  = (const float*)d_in[0];
  const float* kc = (const float*)d_in[1];
  const float* vc = (const float*)d_in[2];
  const int* bt   = (const int*)d_in[3];
  const int* sl   = (const int*)d_in[4];
  float* out = (float*)d_out;

  size_t half = (size_t)NSEQ * HKVN * SKV * DH;
  size_t need = 2 * half * sizeof(bf16);
  if (ws_size >= need) {
    bf16* kb = (bf16*)d_ws;
    bf16* vt = kb + half;
    hipLaunchKernelGGL(prep_k, dim3(4096), dim3(256), 0, stream, kc, bt, kb);
    hipLaunchKernelGGL(prep_vt, dim3(1024), dim3(256), 0, stream, vc, bt, vt);
    hipLaunchKernelGGL((attn_kern<true>), dim3(512), dim3(256), 0, stream,
                       q, kc, vc, bt, sl, kb, vt, out);
  } else {
    hipLaunchKernelGGL((attn_kern<false>), dim3(512), dim3(256), 0, stream,
                       q, kc, vc, bt, sl, (const bf16*)nullptr, (const bf16*)nullptr, out);
  }
}

// Round 15
// 116.638 us; speedup vs baseline: 4.1975x; 1.0465x over previous
//
#include <hip/hip_runtime.h>
#include <hip/hip_bf16.h>

typedef __bf16 bf16;
typedef __attribute__((ext_vector_type(8))) __bf16 bf16x8;
typedef __attribute__((ext_vector_type(4))) __bf16 bf16x4;
typedef __attribute__((ext_vector_type(4))) float f32x4;

static constexpr int NSEQ = 4;
static constexpr int LQ   = 512;
static constexpr int HQN  = 32;
static constexpr int HKVN = 8;
static constexpr int GQ   = 4;
static constexpr int DH   = 128;
static constexpr int BPS  = 64;     // blocks per sequence (2048/32)
static constexpr int SKV  = 2048;   // max kv length
static constexpr int KVB  = 64;     // kv tile (2 paged blocks)
static constexpr int QBL  = 32;     // l-rows per workgroup (per wave, 1 g head each)
static constexpr int VST  = 72;     // V LDS row stride (elems)

__device__ __forceinline__ bf16x8 cvt8(const float4& a, const float4& b) {
  bf16x8 o;
  o[0] = (bf16)a.x; o[1] = (bf16)a.y; o[2] = (bf16)a.z; o[3] = (bf16)a.w;
  o[4] = (bf16)b.x; o[5] = (bf16)b.y; o[6] = (bf16)b.z; o[7] = (bf16)b.w;
  return o;
}

// prepass 1: gather paged K + convert to bf16: kb[b][h][s][d]
__global__ void prep_k(const float* __restrict__ kc, const int* __restrict__ bt,
                       bf16* __restrict__ kb) {
  int e = (blockIdx.x * 256 + threadIdx.x) * 8;
  int d = e & 127;
  int s = (e >> 7) & 2047;
  int h = (e >> 18) & 7;
  int b = e >> 21;
  int pb = bt[b * BPS + (s >> 5)];
  const float* src = kc + (((size_t)pb * 32 + (s & 31)) * 8 + h) * 128 + d;
  float4 a = *(const float4*)src;
  float4 c = *(const float4*)(src + 4);
  *(bf16x8*)(kb + e) = cvt8(a, c);
}

// prepass 2: gather paged V + convert + transpose: vt[b][h][d][s]
__global__ void prep_vt(const float* __restrict__ vc, const int* __restrict__ bt,
                        bf16* __restrict__ vt) {
  __shared__ __align__(16) bf16 T[64][136];
  int bid = blockIdx.x;
  int st = bid & 31;
  int h  = (bid >> 5) & 7;
  int b  = bid >> 8;
  int tid = threadIdx.x;
  {
    int s  = tid >> 2;
    int d0 = (tid & 3) * 32;
    int sg = st * 64 + s;
    int pb = bt[b * BPS + (sg >> 5)];
    const float* src = vc + (((size_t)pb * 32 + (sg & 31)) * 8 + h) * 128 + d0;
#pragma unroll
    for (int k = 0; k < 4; ++k) {
      float4 a = *(const float4*)(src + 8 * k);
      float4 c = *(const float4*)(src + 8 * k + 4);
      *(bf16x8*)&T[s][d0 + 8 * k] = cvt8(a, c);
    }
  }
  __syncthreads();
  {
    int d  = tid & 127;
    int g2 = tid >> 7;
    bf16* dst = vt + (((size_t)(b * 8 + h)) * 128 + d) * SKV + st * 64 + g2 * 32;
#pragma unroll
    for (int k = 0; k < 4; ++k) {
      bf16x8 o;
#pragma unroll
      for (int j = 0; j < 8; ++j) o[j] = T[g2 * 32 + k * 8 + j][d];
      *(bf16x8*)(dst + 8 * k) = o;
    }
  }
}

// flash attention (R9 restore — measured optimum of the explored space):
// 1 workgroup = (b, h, 32 l-rows); wave w = GQA head g = w. Swapped QK^T
// (A=K, B=Q, 16x16x32) -> S^T fragment; softmax in-register (defer-max T13);
// PV via k-PERMUTED 16x16x32 MFMA: the same k-slot permutation pi on A and B
// leaves the contraction invariant; pi is picked so the A-fragment equals the
// values already in accS (plain f32->bf16 cast, zero cross-lane). V LDS uses
// an XOR granule swizzle (T2). Double-buffered K/V, one barrier/tile (T14).
// setprio around MFMA (T5): +4% on THIS structure (R9 vs R14 A/B) — waves
// de-phase via defer-max divergence, so the scheduler has work to arbitrate.
// 2 waves/SIMD is the measured stable operating point (R8/R11/R12/R13 all
// regressed trying to exceed it: staging-doubling / spill / spill / conflicts).
template <bool WS>
__global__ __launch_bounds__(256, 2)
void attn_kern(const float* __restrict__ q, const float* __restrict__ kc,
               const float* __restrict__ vc, const int* __restrict__ bt,
               const int* __restrict__ seq_lens, const bf16* __restrict__ kb,
               const bf16* __restrict__ vtb, float* __restrict__ out) {
  __shared__ __align__(16) bf16 Kl[2][64][136];        // [buf][s][d]
  __shared__ __align__(16) bf16 Vl[2][128 * VST];      // [buf][d][s] swizzled

  // bid mapping: bid & bid+256 are complementary qtiles (work sum const),
  // 4 (b,h) combos per XCD residue for L2 locality.
  int bid = (int)blockIdx.x;
  int hi  = bid >> 8;
  int u   = bid & 255;
  int xcd = u & 7;
  int k2  = u >> 3;
  int c   = (k2 >> 3) | (xcd << 2);
  int i   = k2 & 7;
  int qt  = hi ? (15 - i) : i;
  int h   = c & 7;
  int b   = c >> 3;
  int lb  = qt * QBL;

  int tid  = (int)threadIdx.x;
  int w    = tid >> 6;
  int lane = tid & 63;
  int lq   = lane & 15;
  int lg   = lane >> 4;

  int ctx = seq_lens[b] - LQ;
  int nt  = (ctx + lb + QBL + KVB - 1) / KVB;

  const float CEXP = 0.08838834764831843f * 1.44269504088896340f;
  const float TH8  = 8.0f / CEXP;

  // Q fragments (B-operand): lane holds Q[lb + n*16 + lq][kk*32 + lg*8 + j]
  int hq = h * GQ + w;
  bf16x8 qf[2][4];
#pragma unroll
  for (int n = 0; n < 2; ++n) {
    const float* qp = q + (((size_t)(b * LQ + lb + n * 16 + lq)) * HQN + hq) * DH + lg * 8;
#pragma unroll
    for (int kk = 0; kk < 4; ++kk) {
      float4 a = *(const float4*)(qp + kk * 32);
      float4 c2 = *(const float4*)(qp + kk * 32 + 4);
      qf[n][kk] = cvt8(a, c2);
    }
  }

  f32x4 accO[2][8];
  f32x4 zero = {0.f, 0.f, 0.f, 0.f};
#pragma unroll
  for (int m = 0; m < 2; ++m)
#pragma unroll
    for (int nd = 0; nd < 8; ++nd) accO[m][nd] = zero;
  float mrun[2] = {-1e30f, -1e30f};
  float lrun[2] = {0.f, 0.f};

  const int* btr = bt + b * BPS;
  const bf16* kbase = WS ? kb  + (size_t)(b * 8 + h) * SKV * DH : nullptr;
  const bf16* vbase = WS ? vtb + (size_t)(b * 8 + h) * DH * SKV : nullptr;

  // staging geometry
  int ks_ = tid >> 2, kd0 = (tid & 3) * 32;   // K: [s][d] rows
  int vd_ = tid >> 1, vu  = tid & 1;          // V^T: [d][s] rows, col half
  int vxw = ((vd_ >> 3) & 3) << 1;            // write-side granule XOR

  bf16x8 kpre[4], vpre[4];
  auto ldKV = [&](int t) {
    const bf16* ks = kbase + ((size_t)t * 64 + ks_) * DH + kd0;
#pragma unroll
    for (int k = 0; k < 4; ++k) kpre[k] = *(const bf16x8*)(ks + 8 * k);
    const bf16* vs = vbase + (size_t)vd_ * SKV + t * 64 + vu * 32;
#pragma unroll
    for (int k = 0; k < 4; ++k) vpre[k] = *(const bf16x8*)(vs + 8 * k);
  };
  auto stKV = [&](int bb) {
#pragma unroll
    for (int k = 0; k < 4; ++k) *(bf16x8*)&Kl[bb][ks_][kd0 + 8 * k] = kpre[k];
#pragma unroll
    for (int k = 0; k < 4; ++k) {
      int g = (4 * vu + k) ^ vxw;             // swizzled 8-elem granule
      *(bf16x8*)&Vl[bb][vd_ * VST + (g << 3)] = vpre[k];
    }
  };

  auto compute = [&](int t, int bb) {
    // ---- QK^T (swapped): S^T rows s = t*64+m*16+lg*4+r, col q = n*16+lq ----
    f32x4 accS[4][2];
#pragma unroll
    for (int m = 0; m < 4; ++m)
#pragma unroll
      for (int n = 0; n < 2; ++n) accS[m][n] = zero;
    __builtin_amdgcn_s_setprio(1);
#pragma unroll
    for (int m = 0; m < 4; ++m) {
      bf16x8 ak[4];
#pragma unroll
      for (int kk = 0; kk < 4; ++kk)
        ak[kk] = *(const bf16x8*)&Kl[bb][m * 16 + lq][kk * 32 + lg * 8];
#pragma unroll
      for (int n = 0; n < 2; ++n)
#pragma unroll
        for (int kk = 0; kk < 4; ++kk)
          accS[m][n] = __builtin_amdgcn_mfma_f32_16x16x32_bf16(ak[kk], qf[n][kk], accS[m][n], 0, 0, 0);
    }
    __builtin_amdgcn_s_setprio(0);

    // ---- causal mask (boundary tiles only) ----
    if (t * KVB + KVB - 1 > ctx + lb) {
#pragma unroll
      for (int m = 0; m < 4; ++m) {
        int sg = t * 64 + m * 16 + lg * 4;
#pragma unroll
        for (int n = 0; n < 2; ++n) {
          int qpos = ctx + lb + n * 16 + lq;
#pragma unroll
          for (int r = 0; r < 4; ++r)
            if (sg + r > qpos) accS[m][n][r] = -1e30f;
        }
      }
    }

    // ---- online softmax (per q column = lane&15), defer-max ----
#pragma unroll
    for (int n = 0; n < 2; ++n) {
      float mx = accS[0][n][0];
#pragma unroll
      for (int m = 0; m < 4; ++m)
#pragma unroll
        for (int r = 0; r < 4; ++r) mx = fmaxf(mx, accS[m][n][r]);
      mx = fmaxf(mx, __shfl_xor(mx, 16));
      mx = fmaxf(mx, __shfl_xor(mx, 32));
      if (!__all(mx <= mrun[n] + TH8)) {
        float mnew = fmaxf(mrun[n], mx);
        float corr = exp2f((mrun[n] - mnew) * CEXP);
        mrun[n] = mnew;
        lrun[n] *= corr;
        float cb[4];
#pragma unroll
        for (int r = 0; r < 4; ++r) cb[r] = __shfl(corr, lg * 4 + r);
#pragma unroll
        for (int nd = 0; nd < 8; ++nd)
#pragma unroll
          for (int r = 0; r < 4; ++r) accO[n][nd][r] *= cb[r];
      }
      float psum = 0.f;
#pragma unroll
      for (int m = 0; m < 4; ++m)
#pragma unroll
        for (int r = 0; r < 4; ++r) {
          float p = exp2f((accS[m][n][r] - mrun[n]) * CEXP);
          psum += p;
          accS[m][n][r] = p;
        }
      lrun[n] += psum;
    }

    // ---- k-permuted A-fragment: slot j of (n,ks) holds
    // P[s = 32ks + 16(j>>2) + 4lg + (j&3)] = accS[2ks + (j>>2)][n][j&3]. ----
    bf16x8 ap[2][2];
#pragma unroll
    for (int n = 0; n < 2; ++n)
#pragma unroll
      for (int ks3 = 0; ks3 < 2; ++ks3) {
#pragma unroll
        for (int e = 0; e < 4; ++e) {
          ap[n][ks3][e]     = (bf16)accS[2 * ks3][n][e];
          ap[n][ks3][4 + e] = (bf16)accS[2 * ks3 + 1][n][e];
        }
      }

    // ---- PV: B slot j of ks = V[s=pi(k)][d], read from swizzled Vl ----
    __builtin_amdgcn_s_setprio(1);
#pragma unroll
    for (int nd = 0; nd < 8; ++nd) {
      int d   = nd * 16 + lq;
      int vxr = ((d >> 3) & 3) << 1;
      int rb  = d * VST + 4 * (lg & 1);
#pragma unroll
      for (int ks3 = 0; ks3 < 2; ++ks3) {
        int g0 = 4 * ks3 + (lg >> 1);
        bf16x4 lo = *(const bf16x4*)&Vl[bb][rb + ((g0 ^ vxr) << 3)];
        bf16x4 hi2 = *(const bf16x4*)&Vl[bb][rb + (((g0 + 2) ^ vxr) << 3)];
        bf16x8 bv;
#pragma unroll
        for (int e = 0; e < 4; ++e) { bv[e] = lo[e]; bv[4 + e] = hi2[e]; }
#pragma unroll
        for (int n = 0; n < 2; ++n)
          accO[n][nd] = __builtin_amdgcn_mfma_f32_16x16x32_bf16(ap[n][ks3], bv, accO[n][nd], 0, 0, 0);
      }
    }
    __builtin_amdgcn_s_setprio(0);
  };

  if (WS) {
    ldKV(0);
    stKV(0);
    if (nt > 1) ldKV(1);
    __syncthreads();
    for (int t = 0; t < nt; ++t) {
      int cur = t & 1;
      if (t + 1 < nt) {
        stKV(cur ^ 1);                 // store t+1 (loads issued last iter)
        if (t + 2 < nt) ldKV(t + 2);
      }
      compute(t, cur);
      __syncthreads();                 // single barrier per tile
    }
  } else {
    for (int t = 0; t < nt; ++t) {
      {
        int s  = tid >> 2;
        int d0 = (tid & 3) * 32;
        int pb = btr[t * 2 + (s >> 5)];
        const float* ksrc = kc + (((size_t)pb * 32 + (s & 31)) * 8 + h) * 128 + d0;
#pragma unroll
        for (int k = 0; k < 4; ++k) {
          float4 a = *(const float4*)(ksrc + 8 * k);
          float4 c2 = *(const float4*)(ksrc + 8 * k + 4);
          *(bf16x8*)&Kl[0][s][d0 + 8 * k] = cvt8(a, c2);
        }
        int d  = tid & 127;
        int sh = tid >> 7;
        int vxf = ((d >> 3) & 3) << 1;
        int pbv = btr[t * 2 + sh];
        const float* vsrc = vc + (((size_t)pbv * 32) * 8 + h) * 128 + d;
#pragma unroll
        for (int k = 0; k < 8; ++k) {
          bf16x4 o;
#pragma unroll
          for (int j = 0; j < 4; ++j) o[j] = (bf16)vsrc[(size_t)(k * 4 + j) * 1024];
          int g = (4 * sh + (k >> 1)) ^ vxf;
          *(bf16x4*)&Vl[0][d * VST + (g << 3) + 4 * (k & 1)] = o;
        }
      }
      __syncthreads();
      compute(t, 0);
      __syncthreads();
    }
  }

  // ---- epilogue: finish row sums, normalize, store f32 ----
#pragma unroll
  for (int n = 0; n < 2; ++n) {
    lrun[n] += __shfl_xor(lrun[n], 16);
    lrun[n] += __shfl_xor(lrun[n], 32);
    lrun[n] = 1.f / lrun[n];
  }
#pragma unroll
  for (int m2 = 0; m2 < 2; ++m2) {
    float rb[4];
#pragma unroll
    for (int r = 0; r < 4; ++r) rb[r] = __shfl(lrun[m2], lg * 4 + r);
#pragma unroll
    for (int r = 0; r < 4; ++r) {
      float* op = out + (((size_t)(b * LQ + lb + m2 * 16 + lg * 4 + r)) * HQN + hq) * DH + lq;
#pragma unroll
      for (int nd = 0; nd < 8; ++nd) op[nd * 16] = accO[m2][nd][r] * rb[r];
    }
  }
}

extern "C" void kernel_launch(void* const* d_in, const int* in_sizes, int n_in,
                              void* d_out, int out_size, void* d_ws, size_t ws_size,
                              hipStream_t stream) {
  const float* q  = (const float*)d_in[0];
  const float* kc = (const float*)d_in[1];
  const float* vc = (const float*)d_in[2];
  const int* bt   = (const int*)d_in[3];
  const int* sl   = (const int*)d_in[4];
  float* out = (float*)d_out;

  size_t half = (size_t)NSEQ * HKVN * SKV * DH;
  size_t need = 2 * half * sizeof(bf16);
  if (ws_size >= need) {
    bf16* kb = (bf16*)d_ws;
    bf16* vt = kb + half;
    hipLaunchKernelGGL(prep_k, dim3(4096), dim3(256), 0, stream, kc, bt, kb);
    hipLaunchKernelGGL(prep_vt, dim3(1024), dim3(256), 0, stream, vc, bt, vt);
    hipLaunchKernelGGL((attn_kern<true>), dim3(512), dim3(256), 0, stream,
                       q, kc, vc, bt, sl, kb, vt, out);
  } else {
    hipLaunchKernelGGL((attn_kern<false>), dim3(512), dim3(256), 0, stream,
                       q, kc, vc, bt, sl, (const bf16*)nullptr, (const bf16*)nullptr, out);
  }
}